// Round 1
// baseline (1951.574 us; speedup 1.0000x reference)
//
#include <hip/hip_runtime.h>

// ---------------------------------------------------------------------------
// Graph-conv LSTM encoder, B=4 T=12 N=4096 F=32, NG=14 gates.
// Strategy: adj->bf16 once (134MB, fits 256MB L3). Precompute Yx = adj@x_t for
// all t (one 384-col GEMM). Per step: GEMM adj@h (32 col), MFMA gate kernel 1
// (gates 0..7 -> c_new, h_mid), GEMM adj@[h_mid|m] (64 col), MFMA gate kernel 2
// (gates 8..13 -> m_new, h_new -> output). V operands stored transposed
// [B, cols, N] bf16 so B-fragments are contiguous 16B loads.
// ---------------------------------------------------------------------------

typedef __bf16 bf16_t;
typedef __bf16 bf16x8 __attribute__((ext_vector_type(8)));
typedef float  f32x4  __attribute__((ext_vector_type(4)));

#define DI __device__ __forceinline__

#define BB 4
#define TT 12
#define NN 4096
#define FF 32

DI float sigm(float x)  { return __builtin_amdgcn_rcpf(1.f + __expf(-x)); }
DI float tanh_f(float x){ float e = __expf(2.f * x); return 1.f - 2.f * __builtin_amdgcn_rcpf(e + 1.f); }

// ---------------- adj fp32 -> bf16 (8 elements / thread) --------------------
__global__ __launch_bounds__(256) void conv_adj_k(const float* __restrict__ a,
                                                  bf16_t* __restrict__ o) {
    size_t i = ((size_t)blockIdx.x * 256 + threadIdx.x) * 8;
    float4 v0 = *(const float4*)(a + i);
    float4 v1 = *(const float4*)(a + i + 4);
    union { uint4 u; bf16_t h[8]; } t;
    t.h[0] = (bf16_t)v0.x; t.h[1] = (bf16_t)v0.y; t.h[2] = (bf16_t)v0.z; t.h[3] = (bf16_t)v0.w;
    t.h[4] = (bf16_t)v1.x; t.h[5] = (bf16_t)v1.y; t.h[6] = (bf16_t)v1.z; t.h[7] = (bf16_t)v1.w;
    *(uint4*)(o + i) = t.u;
}

// ---------------- x [B,T,N,F] fp32 -> xT [B, T*F, N] bf16 -------------------
__global__ __launch_bounds__(256) void xpose_k(const float* __restrict__ x,
                                               bf16_t* __restrict__ xT) {
    const int b = blockIdx.z, t = blockIdx.y, n0 = blockIdx.x * 64;
    const int tid = threadIdx.x;
    __shared__ float tile[64][33];
    const float* src = x + (((size_t)(b * TT + t)) * NN + n0) * FF;
#pragma unroll
    for (int rr = 0; rr < 2; ++rr) {
        int idx = rr * 256 + tid;           // 512 float4 loads = 64 rows x 32 f
        int row = idx >> 3, seg = idx & 7;
        float4 v = *(const float4*)(src + row * FF + seg * 4);
        tile[row][seg * 4 + 0] = v.x; tile[row][seg * 4 + 1] = v.y;
        tile[row][seg * 4 + 2] = v.z; tile[row][seg * 4 + 3] = v.w;
    }
    __syncthreads();
    const int f = tid >> 3, seg = tid & 7;
    union { uint4 u; bf16_t h[8]; } o;
#pragma unroll
    for (int j = 0; j < 8; ++j) o.h[j] = (bf16_t)tile[seg * 8 + j][f];
    *(uint4*)&xT[((size_t)(b * 384 + t * FF + f)) * NN + n0 + seg * 8] = o.u;
}

// ---------------- W [14,32,64] fp32 -> MFMA B-fragments bf16 ----------------
// Wf[((g*4+ct)*64+lane)*8 + j] = W[g][ (lane>>4)*8+j ][ ct*16 + (lane&15) ]
__global__ __launch_bounds__(256) void make_wfrag_k(const float* __restrict__ W,
                                                    bf16_t* __restrict__ Wf) {
    const int g = blockIdx.x, tid = threadIdx.x;
    const int ct = tid >> 6, lane = tid & 63;
    const int k0 = (lane >> 4) * 8, col = ct * 16 + (lane & 15);
    union { uint4 u; bf16_t h[8]; } t;
#pragma unroll
    for (int j = 0; j < 8; ++j) t.h[j] = (bf16_t)W[(g * 32 + k0 + j) * 64 + col];
    *(uint4*)&Wf[((g * 4 + ct) * 64 + lane) * 8] = t.u;
}

// ---------------- init: h=c=m=1 ---------------------------------------------
__global__ __launch_bounds__(256) void init_k(bf16_t* h_bf, bf16_t* hm_bf,
                                              float* c, float* m) {
    const int idx = blockIdx.x * 256 + threadIdx.x;   // B*32*4096 = 524288
    const int b = idx >> 17, r = idx & 131071;
    h_bf[idx] = (bf16_t)1.f;
    hm_bf[(size_t)b * 262144 + 131072 + r] = (bf16_t)1.f;   // m half of [h_mid|m]
    c[idx] = 1.f;
    m[idx] = 1.f;
}

// ---------------- batched GEMM: C[b] = adj[b] @ Vt[b]^T ---------------------
// A: [B,N,N] (bf16 ws copy, or fp32 input converted inline).
// Vt: [B, COLS, N] bf16 (V transposed).  Cout: [B, N, COLS] bf16.
// Block = 256 thr (4 waves), tile ROWS x COLS, K-chunks of 64 with XOR-swizzled
// LDS (chunk' = chunk ^ (row&7)) so b128 reads spread across all banks.
template <int ROWS, int COLS, bool ABF>
__global__ __launch_bounds__(256) void gemm_adj(const void* __restrict__ Ap,
                                                const bf16_t* __restrict__ Vt,
                                                bf16_t* __restrict__ Cout) {
    constexpr int CT = COLS / 16, RT = ROWS / 16, TPW = RT * CT / 4;
    const int b = blockIdx.y;
    const int row0 = blockIdx.x * ROWS;
    const int tid = threadIdx.x, wave = tid >> 6, lane = tid & 63;
    const int mrow = lane & 15, quad = lane >> 4;
    __shared__ __align__(16) bf16_t As[ROWS * 64];
    __shared__ __align__(16) bf16_t Vs[COLS * 64];
    const int rt  = (RT == 4) ? wave : (wave & 1);
    const int ct0 = (RT == 4) ? 0 : (wave >> 1) * TPW;
    const f32x4 zero = {0.f, 0.f, 0.f, 0.f};
    f32x4 acc[TPW];
#pragma unroll
    for (int i = 0; i < TPW; ++i) acc[i] = zero;
    const size_t aoff = ((size_t)b << 24) + (size_t)row0 * NN;

    for (int k0 = 0; k0 < NN; k0 += 64) {
        // stage A chunk [ROWS x 64]
#pragma unroll
        for (int rr = 0; rr < ROWS / 32; ++rr) {
            int idx = rr * 256 + tid;
            int row = idx >> 3, ch = idx & 7, ph = ch ^ (row & 7);
            if constexpr (ABF) {
                *(uint4*)&As[row * 64 + ph * 8] =
                    *(const uint4*)((const bf16_t*)Ap + aoff + (size_t)row * NN + k0 + ch * 8);
            } else {
                const float* s = (const float*)Ap + aoff + (size_t)row * NN + k0 + ch * 8;
                float4 v0 = *(const float4*)s, v1 = *(const float4*)(s + 4);
                union { uint4 u; bf16_t h[8]; } tv;
                tv.h[0] = (bf16_t)v0.x; tv.h[1] = (bf16_t)v0.y; tv.h[2] = (bf16_t)v0.z; tv.h[3] = (bf16_t)v0.w;
                tv.h[4] = (bf16_t)v1.x; tv.h[5] = (bf16_t)v1.y; tv.h[6] = (bf16_t)v1.z; tv.h[7] = (bf16_t)v1.w;
                *(uint4*)&As[row * 64 + ph * 8] = tv.u;
            }
        }
        // stage V chunk [COLS x 64] from Vt
#pragma unroll
        for (int rr = 0; rr < COLS / 32; ++rr) {
            int idx = rr * 256 + tid;
            int col = idx >> 3, ch = idx & 7, ph = ch ^ (col & 7);
            *(uint4*)&Vs[col * 64 + ph * 8] =
                *(const uint4*)(Vt + ((size_t)b * COLS + col) * NN + k0 + ch * 8);
        }
        __syncthreads();
#pragma unroll
        for (int s = 0; s < 2; ++s) {
            const int arow = rt * 16 + mrow;
            const int ach = s * 4 + quad;
            bf16x8 af = *(const bf16x8*)&As[arow * 64 + (ach ^ (arow & 7)) * 8];
#pragma unroll
            for (int i = 0; i < TPW; ++i) {
                const int col = (ct0 + i) * 16 + mrow;
                bf16x8 bf = *(const bf16x8*)&Vs[col * 64 + (ach ^ (col & 7)) * 8];
                acc[i] = __builtin_amdgcn_mfma_f32_16x16x32_bf16(af, bf, acc[i], 0, 0, 0);
            }
        }
        __syncthreads();
    }
#pragma unroll
    for (int i = 0; i < TPW; ++i) {
        const int col = (ct0 + i) * 16 + mrow;
#pragma unroll
        for (int r = 0; r < 4; ++r) {
            const int row = row0 + rt * 16 + quad * 4 + r;
            Cout[((size_t)b * NN + row) * COLS + col] = (bf16_t)acc[i][r];
        }
    }
}

// ---------------- gate kernel 1: gates 0..7 -> c_new, h_mid -----------------
// Wave handles 16 n-rows. z = y@W via MFMA (A = y rows frag, B = Wf frag).
// GLU pairing is register-local: col c in tile ct, col c+32 in tile ct+2.
__global__ __launch_bounds__(256) void gates1_k(const bf16_t* __restrict__ Yx,
                                                const bf16_t* __restrict__ Yh,
                                                const bf16_t* __restrict__ Wf,
                                                const float* __restrict__ bias,
                                                float* __restrict__ c,
                                                bf16_t* __restrict__ hm_bf, int t) {
    const int b = blockIdx.y, n0 = blockIdx.x * 64;
    const int tid = threadIdx.x, wave = tid >> 6, lane = tid & 63;
    const int mrow = lane & 15, quad = lane >> 4;
    const int nw = n0 + wave * 16;
    const f32x4 zero = {0.f, 0.f, 0.f, 0.f};
    bf16x8 ax = *(const bf16x8*)&Yx[((size_t)b * NN + nw + mrow) * 384 + t * FF + quad * 8];
    bf16x8 ah = *(const bf16x8*)&Yh[((size_t)b * NN + nw + mrow) * FF + quad * 8];
    float gate[4][2][4];   // f, i, cg(tanh), o
#pragma unroll
    for (int gi = 0; gi < 4; ++gi) {
        const int ge = 2 * gi, go = ge + 1;
        f32x4 ze[4], zo[4];
#pragma unroll
        for (int ct = 0; ct < 4; ++ct) {
            bf16x8 we = *(const bf16x8*)&Wf[((ge * 4 + ct) * 64 + lane) * 8];
            bf16x8 wo = *(const bf16x8*)&Wf[((go * 4 + ct) * 64 + lane) * 8];
            ze[ct] = __builtin_amdgcn_mfma_f32_16x16x32_bf16(ax, we, zero, 0, 0, 0);
            zo[ct] = __builtin_amdgcn_mfma_f32_16x16x32_bf16(ah, wo, zero, 0, 0, 0);
            const float be = bias[ge * 64 + ct * 16 + mrow];
            const float bo = bias[go * 64 + ct * 16 + mrow];
#pragma unroll
            for (int r = 0; r < 4; ++r) { ze[ct][r] += be; zo[ct][r] += bo; }
        }
#pragma unroll
        for (int p = 0; p < 2; ++p)
#pragma unroll
            for (int r = 0; r < 4; ++r) {
                float s = ze[p][r] * sigm(ze[p + 2][r]) + zo[p][r] * sigm(zo[p + 2][r]);
                gate[gi][p][r] = (gi == 2) ? tanh_f(s) : sigm(s);
            }
    }
    __shared__ bf16_t hmT[32][64];
#pragma unroll
    for (int p = 0; p < 2; ++p)
#pragma unroll
        for (int r = 0; r < 4; ++r) {
            const int row = nw + quad * 4 + r, col = p * 16 + mrow;
            const size_t ci = ((size_t)b * NN + row) * FF + col;
            float cn = gate[0][p][r] * c[ci] + gate[1][p][r] * gate[2][p][r];
            c[ci] = cn;
            hmT[col][wave * 16 + quad * 4 + r] = (bf16_t)(gate[3][p][r] * tanh_f(cn));
        }
    __syncthreads();
    {   // transposed coalesced write: hm_bf[b][col][n]
        const int col = tid >> 3, seg = tid & 7;
        union { uint4 u; bf16_t h[8]; } o;
#pragma unroll
        for (int j = 0; j < 8; ++j) o.h[j] = hmT[col][seg * 8 + j];
        *(uint4*)&hm_bf[((size_t)b * 64 + col) * NN + n0 + seg * 8] = o.u;
    }
}

// ---------------- gate kernel 2: gates 8..13 -> m_new, h_new ----------------
__global__ __launch_bounds__(256) void gates2_k(const bf16_t* __restrict__ Y2,
                                                const bf16_t* __restrict__ Wf,
                                                const float* __restrict__ bias,
                                                float* __restrict__ m,
                                                bf16_t* __restrict__ hm_bf,
                                                bf16_t* __restrict__ h_bf,
                                                float* __restrict__ hs, int t) {
    const int b = blockIdx.y, n0 = blockIdx.x * 64;
    const int tid = threadIdx.x, wave = tid >> 6, lane = tid & 63;
    const int mrow = lane & 15, quad = lane >> 4;
    const int nw = n0 + wave * 16;
    const f32x4 zero = {0.f, 0.f, 0.f, 0.f};
    bf16x8 axh = *(const bf16x8*)&Y2[((size_t)b * NN + nw + mrow) * 64 + quad * 8];
    bf16x8 axm = *(const bf16x8*)&Y2[((size_t)b * NN + nw + mrow) * 64 + 32 + quad * 8];
    float gate[3][2][4];   // i2, gg, o2 (all sigmoid)
#pragma unroll
    for (int gi = 0; gi < 3; ++gi) {
        const int ge = 8 + 2 * gi, go = ge + 1;
        f32x4 ze[4], zo[4];
#pragma unroll
        for (int ct = 0; ct < 4; ++ct) {
            bf16x8 we = *(const bf16x8*)&Wf[((ge * 4 + ct) * 64 + lane) * 8];
            bf16x8 wo = *(const bf16x8*)&Wf[((go * 4 + ct) * 64 + lane) * 8];
            ze[ct] = __builtin_amdgcn_mfma_f32_16x16x32_bf16(axh, we, zero, 0, 0, 0);
            zo[ct] = __builtin_amdgcn_mfma_f32_16x16x32_bf16(axm, wo, zero, 0, 0, 0);
            const float be = bias[ge * 64 + ct * 16 + mrow];
            const float bo = bias[go * 64 + ct * 16 + mrow];
#pragma unroll
            for (int r = 0; r < 4; ++r) { ze[ct][r] += be; zo[ct][r] += bo; }
        }
#pragma unroll
        for (int p = 0; p < 2; ++p)
#pragma unroll
            for (int r = 0; r < 4; ++r) {
                float s = ze[p][r] * sigm(ze[p + 2][r]) + zo[p][r] * sigm(zo[p + 2][r]);
                gate[gi][p][r] = sigm(s);
            }
    }
    __shared__ bf16_t mT[32][64];
    __shared__ bf16_t hT[32][64];
#pragma unroll
    for (int p = 0; p < 2; ++p)
#pragma unroll
        for (int r = 0; r < 4; ++r) {
            const int row = nw + quad * 4 + r, col = p * 16 + mrow;
            const size_t ci = ((size_t)b * NN + row) * FF + col;
            const float i2 = gate[0][p][r], gg = gate[1][p][r], o2 = gate[2][p][r];
            float mn = i2 * m[ci] + (1.f - i2) * gg;
            m[ci] = mn;
            float hn = mn * o2;
            hs[(((size_t)b * TT + t) * NN + row) * FF + col] = hn;
            mT[col][wave * 16 + quad * 4 + r] = (bf16_t)mn;
            hT[col][wave * 16 + quad * 4 + r] = (bf16_t)hn;
        }
    __syncthreads();
    {
        const int col = tid >> 3, seg = tid & 7;
        union { uint4 u; bf16_t h[8]; } om, oh;
#pragma unroll
        for (int j = 0; j < 8; ++j) { om.h[j] = mT[col][seg * 8 + j]; oh.h[j] = hT[col][seg * 8 + j]; }
        *(uint4*)&hm_bf[((size_t)b * 64 + 32 + col) * NN + n0 + seg * 8] = om.u;
        *(uint4*)&h_bf[((size_t)b * FF + col) * NN + n0 + seg * 8] = oh.u;
    }
}

// ---------------- tail: last_h / last_c / last_m ----------------------------
__global__ __launch_bounds__(256) void finalize_k(const float* __restrict__ hs,
                                                  const float* __restrict__ c,
                                                  const float* __restrict__ m,
                                                  float* __restrict__ tail) {
    const int idx = blockIdx.x * 256 + threadIdx.x;   // 524288
    const int b = idx >> 17, r = idx & 131071;
    tail[idx] = hs[((size_t)b * TT + (TT - 1)) * 131072 + r];
    tail[524288 + idx] = c[idx];
    tail[1048576 + idx] = m[idx];
}

// ---------------------------------------------------------------------------
extern "C" void kernel_launch(void* const* d_in, const int* in_sizes, int n_in,
                              void* d_out, int out_size, void* d_ws, size_t ws_size,
                              hipStream_t stream) {
    const float* x    = (const float*)d_in[0];   // [4,12,4096,32]
    const float* adj  = (const float*)d_in[1];   // [4,4096,4096]
    const float* W    = (const float*)d_in[2];   // [14,32,64]
    const float* bias = (const float*)d_in[3];   // [14,64]
    float* out = (float*)d_out;

    char* ws = (char*)d_ws;
    size_t off = 0;
    auto carve = [&](size_t bytes) -> void* {
        void* p = ws + off;
        off += (bytes + 255) & ~(size_t)255;
        return p;
    };
    bf16_t* xT    = (bf16_t*)carve((size_t)BB * 384 * NN * 2);   // 12.6 MB
    bf16_t* Yx    = (bf16_t*)carve((size_t)BB * NN * 384 * 2);   // 12.6 MB
    bf16_t* Yh    = (bf16_t*)carve((size_t)BB * NN * FF * 2);    // 1 MB
    bf16_t* Y2    = (bf16_t*)carve((size_t)BB * NN * 64 * 2);    // 2 MB
    bf16_t* h_bf  = (bf16_t*)carve((size_t)BB * FF * NN * 2);    // 1 MB
    bf16_t* hm_bf = (bf16_t*)carve((size_t)BB * 64 * NN * 2);    // 2 MB
    bf16_t* Wf    = (bf16_t*)carve((size_t)14 * 4 * 64 * 8 * 2);
    float*  cbuf  = (float*)carve((size_t)BB * NN * FF * 4);     // 2 MB
    float*  mbuf  = (float*)carve((size_t)BB * NN * FF * 4);     // 2 MB
    const size_t adj_bytes = (size_t)BB * NN * NN * 2;           // 134 MB
    const bool abf = (ws_size >= off + adj_bytes);
    bf16_t* adj_bf = abf ? (bf16_t*)carve(adj_bytes) : nullptr;

    if (abf) conv_adj_k<<<32768, 256, 0, stream>>>(adj, adj_bf);
    make_wfrag_k<<<14, 256, 0, stream>>>(W, Wf);
    xpose_k<<<dim3(64, TT, BB), 256, 0, stream>>>(x, xT);
    init_k<<<2048, 256, 0, stream>>>(h_bf, hm_bf, cbuf, mbuf);

    // Precompute Yx = adj @ x_t for all t (COLS = T*F = 384)
    if (abf) gemm_adj<64, 384, true ><<<dim3(64, BB), 256, 0, stream>>>(adj_bf, xT, Yx);
    else     gemm_adj<64, 384, false><<<dim3(64, BB), 256, 0, stream>>>(adj,    xT, Yx);

    for (int t = 0; t < TT; ++t) {
        if (abf) gemm_adj<32, 32, true ><<<dim3(128, BB), 256, 0, stream>>>(adj_bf, h_bf, Yh);
        else     gemm_adj<32, 32, false><<<dim3(128, BB), 256, 0, stream>>>(adj,    h_bf, Yh);
        gates1_k<<<dim3(64, BB), 256, 0, stream>>>(Yx, Yh, Wf, bias, cbuf, hm_bf, t);
        if (abf) gemm_adj<32, 64, true ><<<dim3(128, BB), 256, 0, stream>>>(adj_bf, hm_bf, Y2);
        else     gemm_adj<32, 64, false><<<dim3(128, BB), 256, 0, stream>>>(adj,    hm_bf, Y2);
        gates2_k<<<dim3(64, BB), 256, 0, stream>>>(Y2, Wf, bias, mbuf, hm_bf, h_bf, out, t);
    }
    finalize_k<<<2048, 256, 0, stream>>>(out, cbuf, mbuf, out + (size_t)BB * TT * NN * FF);
}

// Round 2
// 1413.055 us; speedup vs baseline: 1.3811x; 1.3811x over previous
//
#include <hip/hip_runtime.h>

// ---------------------------------------------------------------------------
// Graph-conv LSTM encoder, B=4 T=12 N=4096 F=32, NG=14 gates.
// R2: adj->bf16 once (134MB, L3-resident). No precompute pass: per step
// GEMM1 = adj@[h | x_t] (64 cols), GEMM2 = adj@[h_mid | m] (64 cols), each a
// split-K (4 slices) kernel: A streamed direct from global (no LDS), B panel
// LDS-staged in 256-K chunks, fp32 atomicAdd epilogue -> 1024 blocks, 4/CU.
// Gates kernels consume fp32 Y and zero it in place for the next step.
// ---------------------------------------------------------------------------

typedef __bf16 bf16_t;
typedef __bf16 bf16x8 __attribute__((ext_vector_type(8)));
typedef float  f32x4  __attribute__((ext_vector_type(4)));

#define DI __device__ __forceinline__

#define BB 4
#define TT 12
#define NN 4096
#define FF 32

DI float sigm(float x)  { return __builtin_amdgcn_rcpf(1.f + __expf(-x)); }
DI float tanh_f(float x){ float e = __expf(2.f * x); return 1.f - 2.f * __builtin_amdgcn_rcpf(e + 1.f); }

// ---------------- adj fp32 -> bf16 (8 elements / thread) --------------------
__global__ __launch_bounds__(256) void conv_adj_k(const float* __restrict__ a,
                                                  bf16_t* __restrict__ o) {
    size_t i = ((size_t)blockIdx.x * 256 + threadIdx.x) * 8;
    float4 v0 = *(const float4*)(a + i);
    float4 v1 = *(const float4*)(a + i + 4);
    union { uint4 u; bf16_t h[8]; } t;
    t.h[0] = (bf16_t)v0.x; t.h[1] = (bf16_t)v0.y; t.h[2] = (bf16_t)v0.z; t.h[3] = (bf16_t)v0.w;
    t.h[4] = (bf16_t)v1.x; t.h[5] = (bf16_t)v1.y; t.h[6] = (bf16_t)v1.z; t.h[7] = (bf16_t)v1.w;
    *(uint4*)(o + i) = t.u;
}

// ---------------- x [B,T,N,F] fp32 -> xT [B, T*F, N] bf16 -------------------
__global__ __launch_bounds__(256) void xpose_k(const float* __restrict__ x,
                                               bf16_t* __restrict__ xT) {
    const int b = blockIdx.z, t = blockIdx.y, n0 = blockIdx.x * 64;
    const int tid = threadIdx.x;
    __shared__ float tile[64][33];
    const float* src = x + (((size_t)(b * TT + t)) * NN + n0) * FF;
#pragma unroll
    for (int rr = 0; rr < 2; ++rr) {
        int idx = rr * 256 + tid;
        int row = idx >> 3, seg = idx & 7;
        float4 v = *(const float4*)(src + row * FF + seg * 4);
        tile[row][seg * 4 + 0] = v.x; tile[row][seg * 4 + 1] = v.y;
        tile[row][seg * 4 + 2] = v.z; tile[row][seg * 4 + 3] = v.w;
    }
    __syncthreads();
    const int f = tid >> 3, seg = tid & 7;
    union { uint4 u; bf16_t h[8]; } o;
#pragma unroll
    for (int j = 0; j < 8; ++j) o.h[j] = (bf16_t)tile[seg * 8 + j][f];
    *(uint4*)&xT[((size_t)(b * 384 + t * FF + f)) * NN + n0 + seg * 8] = o.u;
}

// ---------------- W [14,32,64] fp32 -> MFMA B-fragments bf16 ----------------
__global__ __launch_bounds__(256) void make_wfrag_k(const float* __restrict__ W,
                                                    bf16_t* __restrict__ Wf) {
    const int g = blockIdx.x, tid = threadIdx.x;
    const int ct = tid >> 6, lane = tid & 63;
    const int k0 = (lane >> 4) * 8, col = ct * 16 + (lane & 15);
    union { uint4 u; bf16_t h[8]; } t;
#pragma unroll
    for (int j = 0; j < 8; ++j) t.h[j] = (bf16_t)W[(g * 32 + k0 + j) * 64 + col];
    *(uint4*)&Wf[((g * 4 + ct) * 64 + lane) * 8] = t.u;
}

// ---------------- init: h=c=m=1, Y1=Y2=0 ------------------------------------
__global__ __launch_bounds__(256) void init_k(bf16_t* h_bf, bf16_t* hm_bf,
                                              float* c, float* m,
                                              float* Y1, float* Y2) {
    const int idx = blockIdx.x * 256 + threadIdx.x;   // 1,048,576 = B*N*64
    Y1[idx] = 0.f;
    Y2[idx] = 0.f;
    if (idx < 524288) {                               // B*N*32
        const int b = idx >> 17, r = idx & 131071;
        h_bf[idx] = (bf16_t)1.f;
        hm_bf[(size_t)b * 262144 + 131072 + r] = (bf16_t)1.f;   // m half
        c[idx] = 1.f;
        m[idx] = 1.f;
    }
}

// ---------------- split-K GEMM: Y[b] += adj[b] @ [p0 | p1]^T ----------------
// Grid (64 row-tiles, 4 k-slices, B). 256 thr = 4 waves, wave handles 16 rows
// x 64 cols. A direct-global (8 bf16x8 loads in flight), B LDS-staged per
// 256-K chunk with XOR swizzle. Epilogue: fp32 atomicAdd into Y [B,N,64].
template <bool ABF, int S, int BS0, int BS1>
__global__ __launch_bounds__(256, 4) void gemm_splitk(const void* __restrict__ Ap,
                                                      const bf16_t* __restrict__ p0,
                                                      const bf16_t* __restrict__ p1,
                                                      float* __restrict__ Y) {
    const int b = blockIdx.z;
    const int row0 = blockIdx.x * 64;
    const int slice = blockIdx.y;                 // 1024-wide K slice
    const int tid = threadIdx.x, wave = tid >> 6, lane = tid & 63;
    const int mrow = lane & 15, quad = lane >> 4;
    __shared__ __align__(16) bf16_t Vs[64 * 256];
    const f32x4 zero = {0.f, 0.f, 0.f, 0.f};
    f32x4 acc[4];
#pragma unroll
    for (int i = 0; i < 4; ++i) acc[i] = zero;
    const int row = row0 + wave * 16 + mrow;
    const size_t arow = ((size_t)b << 24) + (size_t)row * NN;

    for (int stg = 0; stg < 4; ++stg) {
        const int k0 = slice * 1024 + stg * 256;
        // A fragments for this stage: issued first, complete during staging
        bf16x8 af[8];
        if constexpr (ABF) {
            const bf16_t* ab = (const bf16_t*)Ap + arow + k0 + quad * 8;
#pragma unroll
            for (int s = 0; s < 8; ++s) af[s] = *(const bf16x8*)(ab + s * 32);
        } else {
            const float* ab = (const float*)Ap + arow + k0 + quad * 8;
#pragma unroll
            for (int s = 0; s < 8; ++s) {
                float4 v0 = *(const float4*)(ab + s * 32);
                float4 v1 = *(const float4*)(ab + s * 32 + 4);
                af[s][0] = (bf16_t)v0.x; af[s][1] = (bf16_t)v0.y;
                af[s][2] = (bf16_t)v0.z; af[s][3] = (bf16_t)v0.w;
                af[s][4] = (bf16_t)v1.x; af[s][5] = (bf16_t)v1.y;
                af[s][6] = (bf16_t)v1.z; af[s][7] = (bf16_t)v1.w;
            }
        }
        // stage B panel chunk: 64 cols x 256 k (32 KB), 8 chunks/thread
#pragma unroll
        for (int rr = 0; rr < 8; ++rr) {
            const int idx = rr * 256 + tid;       // 0..2047 16B-chunks
            const int c = idx >> 5, ch = idx & 31;
            const bf16_t* src = (S < 64 && c >= S)
                ? p1 + ((size_t)b * BS1 + (c - S)) * NN
                : p0 + ((size_t)b * BS0 + c) * NN;
            *(uint4*)&Vs[c * 256 + (ch ^ (c & 7)) * 8] =
                *(const uint4*)(src + k0 + ch * 8);
        }
        __syncthreads();
#pragma unroll
        for (int s = 0; s < 8; ++s) {
#pragma unroll
            for (int ct = 0; ct < 4; ++ct) {
                const int c = ct * 16 + mrow;
                bf16x8 bfr = *(const bf16x8*)&Vs[c * 256 + (((s * 4 + quad) ^ (c & 7)) * 8)];
                acc[ct] = __builtin_amdgcn_mfma_f32_16x16x32_bf16(af[s], bfr, acc[ct], 0, 0, 0);
            }
        }
        __syncthreads();
    }
#pragma unroll
    for (int ct = 0; ct < 4; ++ct) {
        const int col = ct * 16 + mrow;
#pragma unroll
        for (int r = 0; r < 4; ++r) {
            const int orow = row0 + wave * 16 + quad * 4 + r;
            unsafeAtomicAdd(&Y[((size_t)b * NN + orow) * 64 + col], acc[ct][r]);
        }
    }
}

// ---------------- gate kernel 1: gates 0..7 -> c_new, h_mid -----------------
// Y1 cols 0..31 = adj@h, 32..63 = adj@x_t (fp32, zeroed in place after read).
__global__ __launch_bounds__(256) void gates1_k(float* __restrict__ Y1,
                                                const bf16_t* __restrict__ Wf,
                                                const float* __restrict__ bias,
                                                float* __restrict__ c,
                                                bf16_t* __restrict__ hm_bf) {
    const int b = blockIdx.y, n0 = blockIdx.x * 64;
    const int tid = threadIdx.x, wave = tid >> 6, lane = tid & 63;
    const int mrow = lane & 15, quad = lane >> 4;
    const int nw = n0 + wave * 16;
    const f32x4 zero = {0.f, 0.f, 0.f, 0.f};
    float* yr = Y1 + ((size_t)b * NN + nw + mrow) * 64;
    float4 h0 = *(float4*)(yr + quad * 8);
    float4 h1 = *(float4*)(yr + quad * 8 + 4);
    float4 x0 = *(float4*)(yr + 32 + quad * 8);
    float4 x1 = *(float4*)(yr + 32 + quad * 8 + 4);
    const float4 z4 = {0.f, 0.f, 0.f, 0.f};
    *(float4*)(yr + quad * 8) = z4;      *(float4*)(yr + quad * 8 + 4) = z4;
    *(float4*)(yr + 32 + quad * 8) = z4; *(float4*)(yr + 32 + quad * 8 + 4) = z4;
    bf16x8 ah, ax;
    ah[0] = (bf16_t)h0.x; ah[1] = (bf16_t)h0.y; ah[2] = (bf16_t)h0.z; ah[3] = (bf16_t)h0.w;
    ah[4] = (bf16_t)h1.x; ah[5] = (bf16_t)h1.y; ah[6] = (bf16_t)h1.z; ah[7] = (bf16_t)h1.w;
    ax[0] = (bf16_t)x0.x; ax[1] = (bf16_t)x0.y; ax[2] = (bf16_t)x0.z; ax[3] = (bf16_t)x0.w;
    ax[4] = (bf16_t)x1.x; ax[5] = (bf16_t)x1.y; ax[6] = (bf16_t)x1.z; ax[7] = (bf16_t)x1.w;
    float gate[4][2][4];   // f, i, cg(tanh), o
#pragma unroll
    for (int gi = 0; gi < 4; ++gi) {
        const int ge = 2 * gi, go = ge + 1;
        f32x4 ze[4], zo[4];
#pragma unroll
        for (int ct = 0; ct < 4; ++ct) {
            bf16x8 we = *(const bf16x8*)&Wf[((ge * 4 + ct) * 64 + lane) * 8];
            bf16x8 wo = *(const bf16x8*)&Wf[((go * 4 + ct) * 64 + lane) * 8];
            ze[ct] = __builtin_amdgcn_mfma_f32_16x16x32_bf16(ax, we, zero, 0, 0, 0);
            zo[ct] = __builtin_amdgcn_mfma_f32_16x16x32_bf16(ah, wo, zero, 0, 0, 0);
            const float be = bias[ge * 64 + ct * 16 + mrow];
            const float bo = bias[go * 64 + ct * 16 + mrow];
#pragma unroll
            for (int r = 0; r < 4; ++r) { ze[ct][r] += be; zo[ct][r] += bo; }
        }
#pragma unroll
        for (int p = 0; p < 2; ++p)
#pragma unroll
            for (int r = 0; r < 4; ++r) {
                float s = ze[p][r] * sigm(ze[p + 2][r]) + zo[p][r] * sigm(zo[p + 2][r]);
                gate[gi][p][r] = (gi == 2) ? tanh_f(s) : sigm(s);
            }
    }
    __shared__ bf16_t hmT[32][64];
#pragma unroll
    for (int p = 0; p < 2; ++p)
#pragma unroll
        for (int r = 0; r < 4; ++r) {
            const int row = nw + quad * 4 + r, col = p * 16 + mrow;
            const size_t ci = ((size_t)b * NN + row) * FF + col;
            float cn = gate[0][p][r] * c[ci] + gate[1][p][r] * gate[2][p][r];
            c[ci] = cn;
            hmT[col][wave * 16 + quad * 4 + r] = (bf16_t)(gate[3][p][r] * tanh_f(cn));
        }
    __syncthreads();
    {   // transposed coalesced write: hm_bf[b][col][n]
        const int col = tid >> 3, seg = tid & 7;
        union { uint4 u; bf16_t h[8]; } o;
#pragma unroll
        for (int j = 0; j < 8; ++j) o.h[j] = hmT[col][seg * 8 + j];
        *(uint4*)&hm_bf[((size_t)b * 64 + col) * NN + n0 + seg * 8] = o.u;
    }
}

// ---------------- gate kernel 2: gates 8..13 -> m_new, h_new ----------------
// Y2 cols 0..31 = adj@h_mid, 32..63 = adj@m (fp32, zeroed after read).
__global__ __launch_bounds__(256) void gates2_k(float* __restrict__ Y2,
                                                const bf16_t* __restrict__ Wf,
                                                const float* __restrict__ bias,
                                                float* __restrict__ m,
                                                bf16_t* __restrict__ hm_bf,
                                                bf16_t* __restrict__ h_bf,
                                                float* __restrict__ hs, int t) {
    const int b = blockIdx.y, n0 = blockIdx.x * 64;
    const int tid = threadIdx.x, wave = tid >> 6, lane = tid & 63;
    const int mrow = lane & 15, quad = lane >> 4;
    const int nw = n0 + wave * 16;
    const f32x4 zero = {0.f, 0.f, 0.f, 0.f};
    float* yr = Y2 + ((size_t)b * NN + nw + mrow) * 64;
    float4 h0 = *(float4*)(yr + quad * 8);
    float4 h1 = *(float4*)(yr + quad * 8 + 4);
    float4 m0 = *(float4*)(yr + 32 + quad * 8);
    float4 m1 = *(float4*)(yr + 32 + quad * 8 + 4);
    const float4 z4 = {0.f, 0.f, 0.f, 0.f};
    *(float4*)(yr + quad * 8) = z4;      *(float4*)(yr + quad * 8 + 4) = z4;
    *(float4*)(yr + 32 + quad * 8) = z4; *(float4*)(yr + 32 + quad * 8 + 4) = z4;
    bf16x8 axh, axm;
    axh[0] = (bf16_t)h0.x; axh[1] = (bf16_t)h0.y; axh[2] = (bf16_t)h0.z; axh[3] = (bf16_t)h0.w;
    axh[4] = (bf16_t)h1.x; axh[5] = (bf16_t)h1.y; axh[6] = (bf16_t)h1.z; axh[7] = (bf16_t)h1.w;
    axm[0] = (bf16_t)m0.x; axm[1] = (bf16_t)m0.y; axm[2] = (bf16_t)m0.z; axm[3] = (bf16_t)m0.w;
    axm[4] = (bf16_t)m1.x; axm[5] = (bf16_t)m1.y; axm[6] = (bf16_t)m1.z; axm[7] = (bf16_t)m1.w;
    float gate[3][2][4];   // i2, gg, o2
#pragma unroll
    for (int gi = 0; gi < 3; ++gi) {
        const int ge = 8 + 2 * gi, go = ge + 1;
        f32x4 ze[4], zo[4];
#pragma unroll
        for (int ct = 0; ct < 4; ++ct) {
            bf16x8 we = *(const bf16x8*)&Wf[((ge * 4 + ct) * 64 + lane) * 8];
            bf16x8 wo = *(const bf16x8*)&Wf[((go * 4 + ct) * 64 + lane) * 8];
            ze[ct] = __builtin_amdgcn_mfma_f32_16x16x32_bf16(axh, we, zero, 0, 0, 0);
            zo[ct] = __builtin_amdgcn_mfma_f32_16x16x32_bf16(axm, wo, zero, 0, 0, 0);
            const float be = bias[ge * 64 + ct * 16 + mrow];
            const float bo = bias[go * 64 + ct * 16 + mrow];
#pragma unroll
            for (int r = 0; r < 4; ++r) { ze[ct][r] += be; zo[ct][r] += bo; }
        }
#pragma unroll
        for (int p = 0; p < 2; ++p)
#pragma unroll
            for (int r = 0; r < 4; ++r) {
                float s = ze[p][r] * sigm(ze[p + 2][r]) + zo[p][r] * sigm(zo[p + 2][r]);
                gate[gi][p][r] = sigm(s);
            }
    }
    __shared__ bf16_t mT[32][64];
    __shared__ bf16_t hT[32][64];
#pragma unroll
    for (int p = 0; p < 2; ++p)
#pragma unroll
        for (int r = 0; r < 4; ++r) {
            const int row = nw + quad * 4 + r, col = p * 16 + mrow;
            const size_t ci = ((size_t)b * NN + row) * FF + col;
            const float i2 = gate[0][p][r], gg = gate[1][p][r], o2 = gate[2][p][r];
            float mn = i2 * m[ci] + (1.f - i2) * gg;
            m[ci] = mn;
            float hn = mn * o2;
            hs[(((size_t)b * TT + t) * NN + row) * FF + col] = hn;
            mT[col][wave * 16 + quad * 4 + r] = (bf16_t)mn;
            hT[col][wave * 16 + quad * 4 + r] = (bf16_t)hn;
        }
    __syncthreads();
    {
        const int col = tid >> 3, seg = tid & 7;
        union { uint4 u; bf16_t h[8]; } om, oh;
#pragma unroll
        for (int j = 0; j < 8; ++j) { om.h[j] = mT[col][seg * 8 + j]; oh.h[j] = hT[col][seg * 8 + j]; }
        *(uint4*)&hm_bf[((size_t)b * 64 + 32 + col) * NN + n0 + seg * 8] = om.u;
        *(uint4*)&h_bf[((size_t)b * FF + col) * NN + n0 + seg * 8] = oh.u;
    }
}

// ---------------- tail: last_h / last_c / last_m ----------------------------
__global__ __launch_bounds__(256) void finalize_k(const float* __restrict__ hs,
                                                  const float* __restrict__ c,
                                                  const float* __restrict__ m,
                                                  float* __restrict__ tail) {
    const int idx = blockIdx.x * 256 + threadIdx.x;   // 524288
    const int b = idx >> 17, r = idx & 131071;
    tail[idx] = hs[((size_t)b * TT + (TT - 1)) * 131072 + r];
    tail[524288 + idx] = c[idx];
    tail[1048576 + idx] = m[idx];
}

// ---------------------------------------------------------------------------
extern "C" void kernel_launch(void* const* d_in, const int* in_sizes, int n_in,
                              void* d_out, int out_size, void* d_ws, size_t ws_size,
                              hipStream_t stream) {
    const float* x    = (const float*)d_in[0];   // [4,12,4096,32]
    const float* adj  = (const float*)d_in[1];   // [4,4096,4096]
    const float* W    = (const float*)d_in[2];   // [14,32,64]
    const float* bias = (const float*)d_in[3];   // [14,64]
    float* out = (float*)d_out;

    char* ws = (char*)d_ws;
    size_t off = 0;
    auto carve = [&](size_t bytes) -> void* {
        void* p = ws + off;
        off += (bytes + 255) & ~(size_t)255;
        return p;
    };
    bf16_t* xT    = (bf16_t*)carve((size_t)BB * 384 * NN * 2);   // 12.6 MB
    float*  Y1    = (float*)carve((size_t)BB * NN * 64 * 4);     // 4 MB
    float*  Y2    = (float*)carve((size_t)BB * NN * 64 * 4);     // 4 MB
    bf16_t* h_bf  = (bf16_t*)carve((size_t)BB * FF * NN * 2);    // 1 MB
    bf16_t* hm_bf = (bf16_t*)carve((size_t)BB * 64 * NN * 2);    // 2 MB
    bf16_t* Wf    = (bf16_t*)carve((size_t)14 * 4 * 64 * 8 * 2);
    float*  cbuf  = (float*)carve((size_t)BB * NN * FF * 4);     // 2 MB
    float*  mbuf  = (float*)carve((size_t)BB * NN * FF * 4);     // 2 MB
    const size_t adj_bytes = (size_t)BB * NN * NN * 2;           // 134 MB
    const bool abf = (ws_size >= off + adj_bytes);
    bf16_t* adj_bf = abf ? (bf16_t*)carve(adj_bytes) : nullptr;

    if (abf) conv_adj_k<<<32768, 256, 0, stream>>>(adj, adj_bf);
    make_wfrag_k<<<14, 256, 0, stream>>>(W, Wf);
    xpose_k<<<dim3(64, TT, BB), 256, 0, stream>>>(x, xT);
    init_k<<<4096, 256, 0, stream>>>(h_bf, hm_bf, cbuf, mbuf, Y1, Y2);

    const dim3 ggrid(64, 4, BB);
    for (int t = 0; t < TT; ++t) {
        const bf16_t* xts = xT + (size_t)t * 32 * NN;
        if (abf) gemm_splitk<true, 32, 32, 384><<<ggrid, 256, 0, stream>>>(adj_bf, h_bf, xts, Y1);
        else     gemm_splitk<false, 32, 32, 384><<<ggrid, 256, 0, stream>>>(adj, h_bf, xts, Y1);
        gates1_k<<<dim3(64, BB), 256, 0, stream>>>(Y1, Wf, bias, cbuf, hm_bf);
        if (abf) gemm_splitk<true, 64, 64, 64><<<ggrid, 256, 0, stream>>>(adj_bf, hm_bf, hm_bf, Y2);
        else     gemm_splitk<false, 64, 64, 64><<<ggrid, 256, 0, stream>>>(adj, hm_bf, hm_bf, Y2);
        gates2_k<<<dim3(64, BB), 256, 0, stream>>>(Y2, Wf, bias, mbuf, hm_bf, h_bf, out, t);
    }
    finalize_k<<<2048, 256, 0, stream>>>(out, cbuf, mbuf, out + (size_t)BB * TT * NN * FF);
}